// Round 4
// baseline (216.390 us; speedup 1.0000x reference)
//
#include <hip/hip_runtime.h>

#define NEGV -1e30f

// Problem constants (fixed by setup_inputs)
constexpr int Bn = 8, Ci = 64, Hn = 64, Wn = 64, Co = 64;
constexpr int HW = Hn * Wn;
constexpr int COB = 4;   // co per thread

// Tiling: lane = col (64), wave = 1 output row, block = 4 waves = 4 rows,
// thread computes 4 co for its pixel -> 4 outputs/thread.
// Grid = 16 hg x 16 cog x 8 b = 2048 blocks = 8 blocks/CU = 8 waves/SIMD
// (needs VGPR<=64 -> __launch_bounds__(256,8)). Latency-hiding via occupancy
// + 1-ci-ahead register prefetch of both x window and weights.
__global__ __launch_bounds__(256, 8)
void maxconv_kernel(const float* __restrict__ x, const float* __restrict__ wt,
                    float* __restrict__ out) {
    const int bid  = blockIdx.x;
    // XCD swizzle: bid%8 == b -> batch plane b stays in one XCD's L2.
    const int b    = bid & 7;
    const int cog  = (bid >> 3) & 15;
    const int hg   = bid >> 7;                  // 0..15
    const int lane = threadIdx.x & 63;
    const int wv   = threadIdx.x >> 6;          // 0..3
    const int h    = hg * 4 + wv;               // wave-uniform output row
    const int co0  = cog * COB;

    const int  cl = lane > 0      ? lane - 1 : 0;     // clamped col offsets
    const int  cr = lane < Wn - 1 ? lane + 1 : Wn - 1;
    const bool eL = (lane == 0), eR = (lane == Wn - 1);
    const bool hasUp = (h > 0);        // wave-uniform
    const bool hasDn = (h < Hn - 1);   // wave-uniform

    const float* xb = x + (size_t)b * Ci * HW;
    int oc = h * Wn + lane;            // 32-bit voffsets, ci=0
    int ol = oc + (cl - lane);
    int orr = oc + (cr - lane);

    float cur[9], nxt[9];              // window regs: rows -1/0/+1 x cols l/c/r
    float wc[COB * 9], wn[COB * 9];    // SGPR weight double-buffer
    float acc[COB];
#pragma unroll
    for (int c = 0; c < COB; c++) acc[c] = NEGV;

    // Pure-load prefetch (no value-dependent ops here: vmcnt wait lands at use)
    auto fetchx = [&](int vl, int vc, int vr, float* w9) {
        if (hasUp) { w9[0] = xb[vl - Wn]; w9[1] = xb[vc - Wn]; w9[2] = xb[vr - Wn]; }
        else       { w9[0] = NEGV;        w9[1] = NEGV;        w9[2] = NEGV; }
        w9[3] = xb[vl]; w9[4] = xb[vc]; w9[5] = xb[vr];
        if (hasDn) { w9[6] = xb[vl + Wn]; w9[7] = xb[vc + Wn]; w9[8] = xb[vr + Wn]; }
        else       { w9[6] = NEGV;        w9[7] = NEGV;        w9[8] = NEGV; }
    };
    // Block-uniform addresses -> scalar (s_load) weight reads
    auto loadw = [&](int ci, float* wbuf) {
#pragma unroll
        for (int c = 0; c < COB; c++) {
            const float* wp = wt + ((size_t)(co0 + c) * Ci + ci) * 9;
#pragma unroll
            for (int k = 0; k < 9; k++) wbuf[c * 9 + k] = wp[k];
        }
    };
    auto compute = [&](const float* w9, const float* wb) {
        // edge fixups here (after the natural vmcnt wait), 6 cndmask
        float l0 = w9[0], l1 = w9[3], l2 = w9[6];
        float r0 = w9[2], r1 = w9[5], r2 = w9[8];
        if (eL) { l0 = NEGV; l1 = NEGV; l2 = NEGV; }
        if (eR) { r0 = NEGV; r1 = NEGV; r2 = NEGV; }
#pragma unroll
        for (int c = 0; c < COB; c++) {
            const float* W = wb + c * 9;
            float t0 = l0    + W[0];
            float t1 = w9[1] + W[1];
            float t2 = r0    + W[2];
            float t3 = l1    + W[3];
            float t4 = w9[4] + W[4];
            float t5 = r1    + W[5];
            float t6 = l2    + W[6];
            float t7 = w9[7] + W[7];
            float t8 = r2    + W[8];
            float a = acc[c];
            a = fmaxf(a, fmaxf(t0, t1));   // v_max3_f32
            a = fmaxf(a, fmaxf(t2, t3));
            a = fmaxf(a, fmaxf(t4, t5));
            a = fmaxf(a, fmaxf(t6, t7));
            a = fmaxf(a, t8);
            acc[c] = a;
        }
    };

    fetchx(ol, oc, orr, cur);
    loadw(0, wc);

#pragma unroll 1
    for (int ci = 0; ci < Ci; ci += 2) {
        ol += HW; oc += HW; orr += HW;
        fetchx(ol, oc, orr, nxt);      // ci+1 window in flight
        loadw(ci + 1, wn);             // ci+1 weights in flight
        compute(cur, wc);              // consume ci
        if (ci + 2 < Ci) {
            ol += HW; oc += HW; orr += HW;
            fetchx(ol, oc, orr, cur);  // ci+2 in flight
            loadw(ci + 2, wc);
        }
        compute(nxt, wn);              // consume ci+1
    }

    // store 4 co planes, lane-coalesced
#pragma unroll
    for (int c = 0; c < COB; c++)
        out[(((size_t)b * Co + co0 + c) * Hn + h) * Wn + lane] = acc[c];
}

extern "C" void kernel_launch(void* const* d_in, const int* in_sizes, int n_in,
                              void* d_out, int out_size, void* d_ws, size_t ws_size,
                              hipStream_t stream) {
    const float* x  = (const float*)d_in[0];
    const float* wt = (const float*)d_in[1];
    float* out = (float*)d_out;

    maxconv_kernel<<<dim3(2048), 256, 0, stream>>>(x, wt, out);
}

// Round 5
// 136.268 us; speedup vs baseline: 1.5880x; 1.5880x over previous
//
#include <hip/hip_runtime.h>

#define NEGV -1e30f

// Problem constants (fixed by setup_inputs)
constexpr int Bn = 8, Ci = 64, Hn = 64, Wn = 64, Co = 64;
constexpr int HW = Hn * Wn;
constexpr int COB = 4;   // co per thread

// lane = col (64), wave = 1 output row, block = 4 waves = 4 rows, 4 co/thread.
// Grid = 16 hg x 16 cog x 8 b = 2048 blocks = 8 blocks/CU = 8 waves/SIMD.
// x window: register double-buffer, prefetched one full ci ahead (pure loads;
// edge cndmask deferred to compute so vmcnt wait lands at first use).
// Weights: INLINE block-uniform reads in the compute loop (R2-proven pattern;
// do NOT buffer them in arrays -- R4 showed the compiler sinks the loads).
__global__ __launch_bounds__(256, 8)
void maxconv_kernel(const float* __restrict__ x, const float* __restrict__ wt,
                    float* __restrict__ out) {
    const int bid  = blockIdx.x;
    // XCD swizzle: bid%8 == b -> batch plane b stays in one XCD's L2
    // (R3/R4-measured: FETCH 33 MB -> 5.3 MB).
    const int b    = bid & 7;
    const int cog  = (bid >> 3) & 15;
    const int hg   = bid >> 7;                  // 0..15
    const int lane = threadIdx.x & 63;
    const int wv   = threadIdx.x >> 6;          // 0..3
    const int h    = hg * 4 + wv;               // wave-uniform output row
    const int co0  = cog * COB;

    const int  cl = lane > 0      ? lane - 1 : 0;     // clamped col offsets
    const int  cr = lane < Wn - 1 ? lane + 1 : Wn - 1;
    const bool eL = (lane == 0), eR = (lane == Wn - 1);
    const bool hasUp = (h > 0);        // wave-uniform
    const bool hasDn = (h < Hn - 1);   // wave-uniform

    const float* xb = x + (size_t)b * Ci * HW;
    const int vc = h * Wn + lane;      // 32-bit element offsets (max 256K)
    const int vl = vc + (cl - lane);
    const int vr = vc + (cr - lane);

    float cur[9], nxt[9];              // window: rows -1/0/+1 x cols l/c/r
    float acc[COB];
#pragma unroll
    for (int c = 0; c < COB; c++) acc[c] = NEGV;

    // Pure-load prefetch; no value-dependent ops so loads stay in flight
    auto fetchx = [&](int off, float* w9) {
        if (hasUp) { w9[0] = xb[vl + off - Wn]; w9[1] = xb[vc + off - Wn]; w9[2] = xb[vr + off - Wn]; }
        else       { w9[0] = NEGV;              w9[1] = NEGV;              w9[2] = NEGV; }
        w9[3] = xb[vl + off]; w9[4] = xb[vc + off]; w9[5] = xb[vr + off];
        if (hasDn) { w9[6] = xb[vl + off + Wn]; w9[7] = xb[vc + off + Wn]; w9[8] = xb[vr + off + Wn]; }
        else       { w9[6] = NEGV;              w9[7] = NEGV;              w9[8] = NEGV; }
    };

    auto compute = [&](const float* w9, int ci) {
        // edge fixups here (after the natural vmcnt wait): 6 cndmask
        float l0 = w9[0], l1 = w9[3], l2 = w9[6];
        float r0 = w9[2], r1 = w9[5], r2 = w9[8];
        if (eL) { l0 = NEGV; l1 = NEGV; l2 = NEGV; }
        if (eR) { r0 = NEGV; r1 = NEGV; r2 = NEGV; }
#pragma unroll
        for (int c = 0; c < COB; c++) {
            // block-uniform address -> scalar weight reads, consumed inline
            const float* wp = wt + ((size_t)(co0 + c) * Ci + ci) * 9;
            float t0 = l0    + wp[0];
            float t1 = w9[1] + wp[1];
            float t2 = r0    + wp[2];
            float t3 = l1    + wp[3];
            float t4 = w9[4] + wp[4];
            float t5 = r1    + wp[5];
            float t6 = l2    + wp[6];
            float t7 = w9[7] + wp[7];
            float t8 = r2    + wp[8];
            float a = acc[c];
            a = fmaxf(a, fmaxf(t0, t1));   // v_max3_f32
            a = fmaxf(a, fmaxf(t2, t3));
            a = fmaxf(a, fmaxf(t4, t5));
            a = fmaxf(a, fmaxf(t6, t7));
            a = fmaxf(a, t8);
            acc[c] = a;
        }
    };

    fetchx(0, cur);

#pragma unroll 1
    for (int ci = 0; ci < Ci; ci += 2) {
        fetchx((ci + 1) * HW, nxt);            // ci+1 window in flight
        compute(cur, ci);                      // consume ci
        if (ci + 2 < Ci) fetchx((ci + 2) * HW, cur);  // ci+2 in flight
        compute(nxt, ci + 1);                  // consume ci+1
    }

    // store 4 co planes, lane-coalesced
#pragma unroll
    for (int c = 0; c < COB; c++)
        out[(((size_t)b * Co + co0 + c) * Hn + h) * Wn + lane] = acc[c];
}

extern "C" void kernel_launch(void* const* d_in, const int* in_sizes, int n_in,
                              void* d_out, int out_size, void* d_ws, size_t ws_size,
                              hipStream_t stream) {
    const float* x  = (const float*)d_in[0];
    const float* wt = (const float*)d_in[1];
    float* out = (float*)d_out;

    maxconv_kernel<<<dim3(2048), 256, 0, stream>>>(x, wt, out);
}

// Round 6
// 128.484 us; speedup vs baseline: 1.6842x; 1.0606x over previous
//
#include <hip/hip_runtime.h>

#define NEGV -1e30f

// Problem constants (fixed by setup_inputs)
constexpr int Bn = 8, Ci = 64, Hn = 64, Wn = 64, Co = 64;
constexpr int HW = Hn * Wn;
constexpr int COB = 2;   // co per thread

// Thread = 4 output cols (float4) x 2 co; wave = 4 rows x 64 cols.
// Per ci per wave: 3 dwordx4 loads (vs 9 dword in R5 = 12x less TA per output),
// col neighbors via DPP row_shr/row_shl (VALU pipe, no lgkm), weights inline
// scalar. Grid = 32 cog x 4 hg x 8 b = 1024 blocks = 4 blocks/CU = 16 waves/CU.
__device__ __forceinline__ float dpp_prev(float v) {  // lane i <- lane i-1 within 16-lane row
    return __int_as_float(__builtin_amdgcn_update_dpp(0, __float_as_int(v), 0x111, 0xF, 0xF, true));
}
__device__ __forceinline__ float dpp_next(float v) {  // lane i <- lane i+1 within 16-lane row
    return __int_as_float(__builtin_amdgcn_update_dpp(0, __float_as_int(v), 0x101, 0xF, 0xF, true));
}

__global__ __launch_bounds__(256, 4)
void maxconv_kernel(const float* __restrict__ x, const float* __restrict__ wt,
                    float* __restrict__ out) {
    const int bid  = blockIdx.x;
    const int b    = bid & 7;          // XCD swizzle: batch plane b pinned to one XCD's L2
    const int rest = bid >> 3;
    const int cog  = rest & 31;        // 32 co-groups
    const int hg   = rest >> 5;        // 0..3
    const int lane = threadIdx.x & 63;
    const int wv   = threadIdx.x >> 6; // 0..3
    const int r    = lane >> 4;        // row within wave
    const int g    = lane & 15;        // col group (matches 16-lane DPP row)
    const int h    = hg * 16 + wv * 4 + r;   // output row
    const int c0   = g * 4;                  // first output col
    const int co0  = cog * COB;

    const bool topE = (h == 0), botE = (h == Hn - 1);
    const bool gL = (g == 0), gR = (g == 15);

    const float* pb = x + (size_t)b * Ci * HW;
    int v0 = h * Wn + c0;              // element offsets, bumped by HW per ci
    int vm = v0 - (topE ? 0 : Wn);     // clamped (value fixed by cndmask below)
    int vp = v0 + (botE ? 0 : Wn);

    float acc[COB][4];
#pragma unroll
    for (int c = 0; c < COB; c++)
#pragma unroll
        for (int p = 0; p < 4; p++) acc[c][p] = NEGV;

#pragma unroll 1
    for (int ci = 0; ci < Ci; ci++) {
        float4 am = *(const float4*)(pb + vm);   // row h-1, cols c0..c0+3
        float4 a0 = *(const float4*)(pb + v0);   // row h
        float4 ap = *(const float4*)(pb + vp);   // row h+1
        vm += HW; v0 += HW; vp += HW;

        // row-edge fixup BEFORE DPP so shifted-in neighbors inherit NEG
        if (topE) { am.x = NEGV; am.y = NEGV; am.z = NEGV; am.w = NEGV; }
        if (botE) { ap.x = NEGV; ap.y = NEGV; ap.z = NEGV; ap.w = NEGV; }

        // col halo from adjacent lanes (same 16-lane DPP row = same image row)
        float Lm = dpp_prev(am.w), L0 = dpp_prev(a0.w), Lp = dpp_prev(ap.w);
        float Rm = dpp_next(am.x), R0 = dpp_next(a0.x), Rp = dpp_next(ap.x);
        if (gL) { Lm = NEGV; L0 = NEGV; Lp = NEGV; }   // plane left edge
        if (gR) { Rm = NEGV; R0 = NEGV; Rp = NEGV; }   // plane right edge

        const float um[6] = { Lm, am.x, am.y, am.z, am.w, Rm };
        const float u0[6] = { L0, a0.x, a0.y, a0.z, a0.w, R0 };
        const float up[6] = { Lp, ap.x, ap.y, ap.z, ap.w, Rp };

#pragma unroll
        for (int c = 0; c < COB; c++) {
            // block-uniform address -> scalar weight reads, consumed inline
            const float* wp = wt + ((size_t)(co0 + c) * Ci + ci) * 9;
            const float w0 = wp[0], w1 = wp[1], w2 = wp[2];
            const float w3 = wp[3], w4 = wp[4], w5 = wp[5];
            const float w6 = wp[6], w7 = wp[7], w8 = wp[8];
#pragma unroll
            for (int p = 0; p < 4; p++) {
                float t0 = um[p]     + w0;
                float t1 = um[p + 1] + w1;
                float t2 = um[p + 2] + w2;
                float t3 = u0[p]     + w3;
                float t4 = u0[p + 1] + w4;
                float t5 = u0[p + 2] + w5;
                float t6 = up[p]     + w6;
                float t7 = up[p + 1] + w7;
                float t8 = up[p + 2] + w8;
                float a = acc[c][p];
                a = fmaxf(a, fmaxf(t0, t1));   // v_max3_f32
                a = fmaxf(a, fmaxf(t2, t3));
                a = fmaxf(a, fmaxf(t4, t5));
                a = fmaxf(a, fmaxf(t6, t7));
                a = fmaxf(a, t8);
                acc[c][p] = a;
            }
        }
    }

    // store: float4 per co, 16 B/lane
#pragma unroll
    for (int c = 0; c < COB; c++) {
        float4 v = make_float4(acc[c][0], acc[c][1], acc[c][2], acc[c][3]);
        *(float4*)(out + (((size_t)b * Co + co0 + c) * Hn + h) * Wn + c0) = v;
    }
}

extern "C" void kernel_launch(void* const* d_in, const int* in_sizes, int n_in,
                              void* d_out, int out_size, void* d_ws, size_t ws_size,
                              hipStream_t stream) {
    const float* x  = (const float*)d_in[0];
    const float* wt = (const float*)d_in[1];
    float* out = (float*)d_out;

    maxconv_kernel<<<dim3(1024), 256, 0, stream>>>(x, wt, out);
}